// Round 4
// baseline (1343.858 us; speedup 1.0000x reference)
//
#include <hip/hip_runtime.h>
#include <hip/hip_bf16.h>

#define NN 50000
#define NE 800000

__device__ __forceinline__ float2 bfp(uint32_t u) {
    union { uint32_t i; float f; } lo, hi;
    lo.i = u << 16;
    hi.i = u & 0xffff0000u;
    return make_float2(lo.f, hi.f);
}

// ---------------------------------------------------------------------------
// Fused node GEMM: q (f32, pre-scaled by 1/8), kv (bf16 interleaved [N,2M]),
// skip (f32). x:[N,K] row-major, W:[K,M].
// ---------------------------------------------------------------------------
template<int K, int M, int NODES>
__global__ __launch_bounds__(128)
void node_gemm_qkvs(const float* __restrict__ x,
                    const float* __restrict__ Wq, const float* __restrict__ bq, float* __restrict__ q,
                    const float* __restrict__ Wk, const float* __restrict__ bk,
                    const float* __restrict__ Wv, const float* __restrict__ bv,
                    __hip_bfloat16* __restrict__ kv,
                    const float* __restrict__ Ws, const float* __restrict__ bs, float* __restrict__ skip)
{
    constexpr int SUBS = 128 / M;        // 1 (M=128) or 2 (M=64)
    constexpr int NPS  = NODES / SUBS;   // nodes per sub-group
    __shared__ float xs[NODES][K];
    const int tid = threadIdx.x;
    const int j   = tid % M;
    const int sub = tid / M;
    const int n0  = blockIdx.x * NODES;

    {
        const float4* xsrc = reinterpret_cast<const float4*>(x + (size_t)n0 * K);
        float4* xdst = reinterpret_cast<float4*>(&xs[0][0]);
        #pragma unroll
        for (int i = 0; i < NODES * K / 4 / 128; ++i)
            xdst[tid + i * 128] = xsrc[tid + i * 128];
    }
    __syncthreads();

    float aq[NPS], ak[NPS], av[NPS], as_[NPS];
    #pragma unroll
    for (int i = 0; i < NPS; ++i) { aq[i] = 0.f; ak[i] = 0.f; av[i] = 0.f; as_[i] = 0.f; }

    for (int r = 0; r < K; ++r) {
        const float wq = Wq[r * M + j];
        const float wk = Wk[r * M + j];
        const float wv = Wv[r * M + j];
        const float ws = Ws[r * M + j];
        #pragma unroll
        for (int i = 0; i < NPS; ++i) {
            const float xv = xs[sub * NPS + i][r];
            aq[i] += xv * wq;
            ak[i] += xv * wk;
            av[i] += xv * wv;
            as_[i] += xv * ws;
        }
    }
    const float bbq = bq[j], bbk = bk[j], bbv = bv[j], bbs = bs[j];
    #pragma unroll
    for (int i = 0; i < NPS; ++i) {
        const int row = n0 + sub * NPS + i;
        q[(size_t)row * M + j]    = (aq[i] + bbq) * 0.125f;   // fold 1/sqrt(C)
        skip[(size_t)row * M + j] = as_[i] + bbs;
        kv[(size_t)row * 2 * M + j]     = __float2bfloat16(ak[i] + bbk);
        kv[(size_t)row * 2 * M + M + j] = __float2bfloat16(av[i] + bbv);
    }
}

// ---------------------------------------------------------------------------
// CSR build: histogram -> scan -> scatter  (counting sort of edges by dst)
// ---------------------------------------------------------------------------
__global__ __launch_bounds__(256)
void hist_dst(const int* __restrict__ dst, int* __restrict__ cnt)
{
    const int e = blockIdx.x * 256 + threadIdx.x;
    if (e < NE) atomicAdd(&cnt[dst[e]], 1);
}

__global__ __launch_bounds__(1024)
void scan_off(const int* __restrict__ cnt, int* __restrict__ off, int* __restrict__ cursor)
{
    __shared__ int part[1024];
    const int tid = threadIdx.x;
    const int C = (NN + 1023) / 1024;
    const int base = tid * C;
    int s = 0;
    for (int i = 0; i < C; ++i) { const int idx = base + i; if (idx < NN) s += cnt[idx]; }
    part[tid] = s;
    __syncthreads();
    const int own = s;
    for (int d = 1; d < 1024; d <<= 1) {
        const int t = (tid >= d) ? part[tid - d] : 0;
        __syncthreads();
        part[tid] += t;
        __syncthreads();
    }
    int run = part[tid] - own;
    for (int i = 0; i < C; ++i) {
        const int idx = base + i;
        if (idx < NN) { off[idx] = run; cursor[idx] = run; run += cnt[idx]; }
    }
    if (tid == 1023) off[NN] = run;
}

__global__ __launch_bounds__(256)
void scatter_edges(const int* __restrict__ dst, int* __restrict__ cursor, int* __restrict__ perm)
{
    const int e = blockIdx.x * 256 + threadIdx.x;
    if (e < NE) { const int p = atomicAdd(&cursor[dst[e]], 1); perm[p] = e; }
}

// ---------------------------------------------------------------------------
// Layer-1 aggregation. One wave per dst node; lane owns channel pair (2l,2l+1);
// head0 = lanes 0-31, head1 = lanes 32-63 (5-step butterfly per 32-half gives
// per-head alpha). We in LDS (keeps VGPR < 64 -> 8 waves/SIMD).
// ---------------------------------------------------------------------------
__global__ __launch_bounds__(256, 8)
void agg_l1(const int* __restrict__ off, const int* __restrict__ perm,
            const int* __restrict__ src, const float* __restrict__ ea,
            const float* __restrict__ We,              // [16,128]
            const float* __restrict__ q,               // [N,128], pre-scaled
            const __hip_bfloat16* __restrict__ kv,     // [N,256] k|v  (bf16)
            const float* __restrict__ skip, float* __restrict__ h)
{
    __shared__ float wes[16 * 128];
    for (int i = threadIdx.x; i < 16 * 128; i += 256) wes[i] = We[i];
    __syncthreads();

    const int node = blockIdx.x * 4 + (threadIdx.x >> 6);
    const int lane = threadIdx.x & 63;
    const int c = lane * 2;

    const size_t nb = (size_t)node * 128;
    const float2 qp = *reinterpret_cast<const float2*>(q + nb + c);
    const float4* ea4 = reinterpret_cast<const float4*>(ea);
    const uint16_t* kvu = reinterpret_cast<const uint16_t*>(kv);

    float acc0 = 0.f, acc1 = 0.f, den = 0.f;
    const int beg = off[node], end = off[node + 1];

    int i = beg;
    for (; i + 1 < end; i += 2) {
        const int eA = perm[i], eB = perm[i + 1];
        const int sA = src[eA], sB = src[eB];
        // issue kv gathers first: they are independent of the eproj compute
        const uint32_t kpA = *reinterpret_cast<const uint32_t*>(kvu + (size_t)sA * 256 + c);
        const uint32_t vpA = *reinterpret_cast<const uint32_t*>(kvu + (size_t)sA * 256 + 128 + c);
        const uint32_t kpB = *reinterpret_cast<const uint32_t*>(kvu + (size_t)sB * 256 + c);
        const uint32_t vpB = *reinterpret_cast<const uint32_t*>(kvu + (size_t)sB * 256 + 128 + c);
        const float4 A0 = ea4[(size_t)eA * 4 + 0], A1 = ea4[(size_t)eA * 4 + 1];
        const float4 A2 = ea4[(size_t)eA * 4 + 2], A3 = ea4[(size_t)eA * 4 + 3];
        const float4 B0 = ea4[(size_t)eB * 4 + 0], B1 = ea4[(size_t)eB * 4 + 1];
        const float4 B2 = ea4[(size_t)eB * 4 + 2], B3 = ea4[(size_t)eB * 4 + 3];
        const float arA[16] = {A0.x,A0.y,A0.z,A0.w, A1.x,A1.y,A1.z,A1.w,
                               A2.x,A2.y,A2.z,A2.w, A3.x,A3.y,A3.z,A3.w};
        const float arB[16] = {B0.x,B0.y,B0.z,B0.w, B1.x,B1.y,B1.z,B1.w,
                               B2.x,B2.y,B2.z,B2.w, B3.x,B3.y,B3.z,B3.w};
        float eA0 = 0.f, eA1 = 0.f, eB0 = 0.f, eB1 = 0.f;
        #pragma unroll
        for (int r = 0; r < 16; ++r) {
            const float2 w = *reinterpret_cast<const float2*>(&wes[r * 128 + c]);
            eA0 += arA[r] * w.x;  eA1 += arA[r] * w.y;
            eB0 += arB[r] * w.x;  eB1 += arB[r] * w.y;
        }
        const float2 kA = bfp(kpA), vA = bfp(vpA), kB = bfp(kpB), vB = bfp(vpB);
        float pA = qp.x * (kA.x + eA0) + qp.y * (kA.y + eA1);
        float pB = qp.x * (kB.x + eB0) + qp.y * (kB.y + eB1);
        #pragma unroll
        for (int m = 1; m < 32; m <<= 1) {
            pA += __shfl_xor(pA, m, 64);
            pB += __shfl_xor(pB, m, 64);
        }
        const float exA = __expf(pA), exB = __expf(pB);
        acc0 += exA * (vA.x + eA0) + exB * (vB.x + eB0);
        acc1 += exA * (vA.y + eA1) + exB * (vB.y + eB1);
        den  += exA + exB;
    }
    if (i < end) {
        const int e = perm[i];
        const int s = src[e];
        const uint32_t kp = *reinterpret_cast<const uint32_t*>(kvu + (size_t)s * 256 + c);
        const uint32_t vp = *reinterpret_cast<const uint32_t*>(kvu + (size_t)s * 256 + 128 + c);
        const float4 A0 = ea4[(size_t)e * 4 + 0], A1 = ea4[(size_t)e * 4 + 1];
        const float4 A2 = ea4[(size_t)e * 4 + 2], A3 = ea4[(size_t)e * 4 + 3];
        const float ar[16] = {A0.x,A0.y,A0.z,A0.w, A1.x,A1.y,A1.z,A1.w,
                              A2.x,A2.y,A2.z,A2.w, A3.x,A3.y,A3.z,A3.w};
        float e0 = 0.f, e1 = 0.f;
        #pragma unroll
        for (int r = 0; r < 16; ++r) {
            const float2 w = *reinterpret_cast<const float2*>(&wes[r * 128 + c]);
            e0 += ar[r] * w.x;  e1 += ar[r] * w.y;
        }
        const float2 kk = bfp(kp), vv = bfp(vp);
        float p = qp.x * (kk.x + e0) + qp.y * (kk.y + e1);
        #pragma unroll
        for (int m = 1; m < 32; m <<= 1) p += __shfl_xor(p, m, 64);
        const float ex = __expf(p);
        acc0 += ex * (vv.x + e0);
        acc1 += ex * (vv.y + e1);
        den  += ex;
    }

    const float inv = 1.f / (den + 1e-16f);
    const float2 sk = *reinterpret_cast<const float2*>(skip + nb + c);
    const float r0 = acc0 * inv + sk.x;
    const float r1 = acc1 * inv + sk.y;
    *reinterpret_cast<float2*>(h + nb + c) = make_float2(fmaxf(r0, 0.f), fmaxf(r1, 0.f));
}

// ---------------------------------------------------------------------------
// Layer-2 aggregation. One wave per dst node; two edges per iteration
// (half-wave each, channel pairs). We in LDS. Writes final output.
// ---------------------------------------------------------------------------
__global__ __launch_bounds__(256, 8)
void agg_l2(const int* __restrict__ off, const int* __restrict__ perm,
            const int* __restrict__ src, const float* __restrict__ ea,
            const float* __restrict__ We,              // [16,64]
            const float* __restrict__ q,               // [N,64], pre-scaled
            const __hip_bfloat16* __restrict__ kv,     // [N,128] k|v (bf16)
            const float* __restrict__ skip, float* __restrict__ out)
{
    __shared__ float wes[16 * 64];
    for (int i = threadIdx.x; i < 16 * 64; i += 256) wes[i] = We[i];
    __syncthreads();

    const int node = blockIdx.x * 4 + (threadIdx.x >> 6);
    const int lane = threadIdx.x & 63;
    const int half = lane >> 5;
    const int hl = lane & 31;
    const int c = hl * 2;

    const size_t nb = (size_t)node * 64;
    const float2 qp = *reinterpret_cast<const float2*>(q + nb + c);
    const float4* ea4 = reinterpret_cast<const float4*>(ea);
    const uint16_t* kvu = reinterpret_cast<const uint16_t*>(kv);

    float acc0 = 0.f, acc1 = 0.f, den = 0.f;
    const int beg = off[node], end = off[node + 1];

    for (int i = beg; i < end; i += 2) {
        const int ii = i + half;
        const bool valid = ii < end;
        const int e = perm[valid ? ii : i];
        const int s = src[e];
        const uint32_t kp = *reinterpret_cast<const uint32_t*>(kvu + (size_t)s * 128 + c);
        const uint32_t vp = *reinterpret_cast<const uint32_t*>(kvu + (size_t)s * 128 + 64 + c);
        const float4 A0 = ea4[(size_t)e * 4 + 0], A1 = ea4[(size_t)e * 4 + 1];
        const float4 A2 = ea4[(size_t)e * 4 + 2], A3 = ea4[(size_t)e * 4 + 3];
        const float ar[16] = {A0.x,A0.y,A0.z,A0.w, A1.x,A1.y,A1.z,A1.w,
                              A2.x,A2.y,A2.z,A2.w, A3.x,A3.y,A3.z,A3.w};
        float e0 = 0.f, e1 = 0.f;
        #pragma unroll
        for (int r = 0; r < 16; ++r) {
            const float2 w = *reinterpret_cast<const float2*>(&wes[r * 64 + c]);
            e0 += ar[r] * w.x;  e1 += ar[r] * w.y;
        }
        const float2 kk = bfp(kp), vv = bfp(vp);
        float p = qp.x * (kk.x + e0) + qp.y * (kk.y + e1);
        #pragma unroll
        for (int m = 1; m < 32; m <<= 1) p += __shfl_xor(p, m, 64);
        const float ex = valid ? __expf(p) : 0.f;
        acc0 += ex * (vv.x + e0);
        acc1 += ex * (vv.y + e1);
        den  += ex;
    }

    acc0 += __shfl_xor(acc0, 32, 64);
    acc1 += __shfl_xor(acc1, 32, 64);
    den  += __shfl_xor(den, 32, 64);

    if (half == 0) {
        const float inv = 1.f / (den + 1e-16f);
        const float2 sk = *reinterpret_cast<const float2*>(skip + nb + c);
        *reinterpret_cast<float2*>(out + nb + c) =
            make_float2(acc0 * inv + sk.x, acc1 * inv + sk.y);
    }
}

extern "C" void kernel_launch(void* const* d_in, const int* in_sizes, int n_in,
                              void* d_out, int out_size, void* d_ws, size_t ws_size,
                              hipStream_t stream) {
    const float* x     = (const float*)d_in[0];
    const int*   ei    = (const int*)  d_in[1];
    const float* eattr = (const float*)d_in[2];
    const float* Wq1 = (const float*)d_in[3],  *bq1 = (const float*)d_in[4];
    const float* Wk1 = (const float*)d_in[5],  *bk1 = (const float*)d_in[6];
    const float* Wv1 = (const float*)d_in[7],  *bv1 = (const float*)d_in[8];
    const float* We1 = (const float*)d_in[9];
    const float* Ws1 = (const float*)d_in[10], *bs1 = (const float*)d_in[11];
    const float* Wq2 = (const float*)d_in[12], *bq2 = (const float*)d_in[13];
    const float* Wk2 = (const float*)d_in[14], *bk2 = (const float*)d_in[15];
    const float* Wv2 = (const float*)d_in[16], *bv2 = (const float*)d_in[17];
    const float* We2 = (const float*)d_in[18];
    const float* Ws2 = (const float*)d_in[19], *bs2 = (const float*)d_in[20];

    const int* srcp = ei;
    const int* dstp = ei + NE;

    // workspace layout
    float* ws = (float*)d_ws;
    const size_t NM1 = (size_t)NN * 128;
    float* q1    = ws;                      // [N,128] f32
    float* skip1 = q1 + NM1;                // [N,128] f32
    float* h     = skip1 + NM1;             // [N,128] f32
    __hip_bfloat16* kv1 = (__hip_bfloat16*)(h + NM1);   // [N,256] bf16
    int* cnt    = (int*)(kv1 + (size_t)NN * 256);
    int* off    = cnt + NN;
    int* cursor = off + NN + 1;
    int* perm   = cursor + NN;
    // layer-2 aliases (stream-ordered reuse of dead layer-1 buffers)
    float* q2    = q1;                      // [N,64]
    float* skip2 = skip1;                   // [N,64]
    __hip_bfloat16* kv2 = kv1;              // [N,128] bf16

    // ---- CSR build (dst-sorted edge permutation), reused by both layers ----
    hipMemsetAsync(cnt, 0, (size_t)NN * sizeof(int), stream);
    hist_dst<<<NE / 256, 256, 0, stream>>>(dstp, cnt);
    scan_off<<<1, 1024, 0, stream>>>(cnt, off, cursor);
    scatter_edges<<<NE / 256, 256, 0, stream>>>(dstp, cursor, perm);

    // ---- layer 1 ----
    node_gemm_qkvs<128, 128, 16><<<NN / 16, 128, 0, stream>>>(
        x, Wq1, bq1, q1, Wk1, bk1, Wv1, bv1, kv1, Ws1, bs1, skip1);
    agg_l1<<<NN / 4, 256, 0, stream>>>(off, perm, srcp, eattr, We1, q1, kv1, skip1, h);

    // ---- layer 2 ----
    node_gemm_qkvs<128, 64, 16><<<NN / 16, 128, 0, stream>>>(
        h, Wq2, bq2, q2, Wk2, bk2, Wv2, bv2, kv2, Ws2, bs2, skip2);
    agg_l2<<<NN / 4, 256, 0, stream>>>(off, perm, srcp, eattr, We2, q2, kv2, skip2, (float*)d_out);
}

// Round 5
// 639.149 us; speedup vs baseline: 2.1026x; 2.1026x over previous
//
#include <hip/hip_runtime.h>
#include <hip/hip_bf16.h>

#define NN 50000
#define NE 800000

__device__ __forceinline__ float2 bfp(uint32_t u) {
    union { uint32_t i; float f; } lo, hi;
    lo.i = u << 16;
    hi.i = u & 0xffff0000u;
    return make_float2(lo.f, hi.f);
}

// ---------------------------------------------------------------------------
// Fused node GEMM: q (f32, pre-scaled by 1/8), kv (bf16 interleaved [N,2M]),
// skip (f32). x:[N,K] row-major, W:[K,M].
// ---------------------------------------------------------------------------
template<int K, int M, int NODES>
__global__ __launch_bounds__(128)
void node_gemm_qkvs(const float* __restrict__ x,
                    const float* __restrict__ Wq, const float* __restrict__ bq, float* __restrict__ q,
                    const float* __restrict__ Wk, const float* __restrict__ bk,
                    const float* __restrict__ Wv, const float* __restrict__ bv,
                    __hip_bfloat16* __restrict__ kv,
                    const float* __restrict__ Ws, const float* __restrict__ bs, float* __restrict__ skip)
{
    constexpr int SUBS = 128 / M;        // 1 (M=128) or 2 (M=64)
    constexpr int NPS  = NODES / SUBS;   // nodes per sub-group
    __shared__ float xs[NODES][K];
    const int tid = threadIdx.x;
    const int j   = tid % M;
    const int sub = tid / M;
    const int n0  = blockIdx.x * NODES;

    {
        const float4* xsrc = reinterpret_cast<const float4*>(x + (size_t)n0 * K);
        float4* xdst = reinterpret_cast<float4*>(&xs[0][0]);
        #pragma unroll
        for (int i = 0; i < NODES * K / 4 / 128; ++i)
            xdst[tid + i * 128] = xsrc[tid + i * 128];
    }
    __syncthreads();

    float aq[NPS], ak[NPS], av[NPS], as_[NPS];
    #pragma unroll
    for (int i = 0; i < NPS; ++i) { aq[i] = 0.f; ak[i] = 0.f; av[i] = 0.f; as_[i] = 0.f; }

    for (int r = 0; r < K; ++r) {
        const float wq = Wq[r * M + j];
        const float wk = Wk[r * M + j];
        const float wv = Wv[r * M + j];
        const float ws = Ws[r * M + j];
        #pragma unroll
        for (int i = 0; i < NPS; ++i) {
            const float xv = xs[sub * NPS + i][r];
            aq[i] += xv * wq;
            ak[i] += xv * wk;
            av[i] += xv * wv;
            as_[i] += xv * ws;
        }
    }
    const float bbq = bq[j], bbk = bk[j], bbv = bv[j], bbs = bs[j];
    #pragma unroll
    for (int i = 0; i < NPS; ++i) {
        const int row = n0 + sub * NPS + i;
        q[(size_t)row * M + j]    = (aq[i] + bbq) * 0.125f;   // fold 1/sqrt(C)
        skip[(size_t)row * M + j] = as_[i] + bbs;
        kv[(size_t)row * 2 * M + j]     = __float2bfloat16(ak[i] + bbk);
        kv[(size_t)row * 2 * M + M + j] = __float2bfloat16(av[i] + bbv);
    }
}

// ---------------------------------------------------------------------------
// CSR build: histogram -> scan -> scatter-with-payload.
// Scatter writes dst-sorted src index and bf16-packed edge_attr rows, so the
// agg kernels stream them sequentially (no perm indirection, no random ea).
// ---------------------------------------------------------------------------
__global__ __launch_bounds__(256)
void hist_dst(const int* __restrict__ dst, int* __restrict__ cnt)
{
    const int e = blockIdx.x * 256 + threadIdx.x;
    if (e < NE) atomicAdd(&cnt[dst[e]], 1);
}

__global__ __launch_bounds__(1024)
void scan_off(const int* __restrict__ cnt, int* __restrict__ off, int* __restrict__ cursor)
{
    __shared__ int part[1024];
    const int tid = threadIdx.x;
    const int C = (NN + 1023) / 1024;
    const int base = tid * C;
    int s = 0;
    for (int i = 0; i < C; ++i) { const int idx = base + i; if (idx < NN) s += cnt[idx]; }
    part[tid] = s;
    __syncthreads();
    const int own = s;
    for (int d = 1; d < 1024; d <<= 1) {
        const int t = (tid >= d) ? part[tid - d] : 0;
        __syncthreads();
        part[tid] += t;
        __syncthreads();
    }
    int run = part[tid] - own;
    for (int i = 0; i < C; ++i) {
        const int idx = base + i;
        if (idx < NN) { off[idx] = run; cursor[idx] = run; run += cnt[idx]; }
    }
    if (tid == 1023) off[NN] = run;
}

__global__ __launch_bounds__(256)
void scatter_edges(const int* __restrict__ dst, const int* __restrict__ src,
                   const float* __restrict__ ea, int* __restrict__ cursor,
                   int* __restrict__ srcs, __hip_bfloat16* __restrict__ eap)
{
    const int e = blockIdx.x * 256 + threadIdx.x;
    if (e >= NE) return;
    const int p = atomicAdd(&cursor[dst[e]], 1);
    srcs[p] = src[e];
    const float4* ea4 = reinterpret_cast<const float4*>(ea) + (size_t)e * 4;
    const float4 a0 = ea4[0], a1 = ea4[1], a2 = ea4[2], a3 = ea4[3];
    const float af[16] = {a0.x,a0.y,a0.z,a0.w, a1.x,a1.y,a1.z,a1.w,
                          a2.x,a2.y,a2.z,a2.w, a3.x,a3.y,a3.z,a3.w};
    __hip_bfloat16 tmp[16];
    #pragma unroll
    for (int r = 0; r < 16; ++r) tmp[r] = __float2bfloat16(af[r]);
    uint4* dp = reinterpret_cast<uint4*>(eap + (size_t)p * 16);
    dp[0] = *reinterpret_cast<const uint4*>(&tmp[0]);
    dp[1] = *reinterpret_cast<const uint4*>(&tmp[8]);
}

// ---------------------------------------------------------------------------
// Layer-1 aggregation. One wave per dst node; lane owns channel pair (2l,2l+1);
// head0 = lanes 0-31, head1 = lanes 32-63. We in LDS. Sequential srcs/eap.
// ---------------------------------------------------------------------------
__global__ __launch_bounds__(256)
void agg_l1(const int* __restrict__ off, const int* __restrict__ srcs,
            const __hip_bfloat16* __restrict__ eap,    // [E,16] bf16, dst-sorted
            const float* __restrict__ We,              // [16,128]
            const float* __restrict__ q,               // [N,128], pre-scaled
            const __hip_bfloat16* __restrict__ kv,     // [N,256] k|v  (bf16)
            const float* __restrict__ skip, float* __restrict__ h)
{
    __shared__ float wes[16 * 128];
    for (int i = threadIdx.x; i < 16 * 128; i += 256) wes[i] = We[i];
    __syncthreads();

    const int node = blockIdx.x * 4 + (threadIdx.x >> 6);
    const int lane = threadIdx.x & 63;
    const int c = lane * 2;

    const size_t nb = (size_t)node * 128;
    const float2 qp = *reinterpret_cast<const float2*>(q + nb + c);
    const uint16_t* kvu = reinterpret_cast<const uint16_t*>(kv);
    const uint4* eaw = reinterpret_cast<const uint4*>(eap);

    float acc0 = 0.f, acc1 = 0.f, den = 0.f;
    const int beg = off[node], end = off[node + 1];

    int i = beg;
    for (; i + 1 < end; i += 2) {
        const int sA = srcs[i], sB = srcs[i + 1];
        // issue kv gathers first: independent of the eproj compute below
        const uint32_t kpA = *reinterpret_cast<const uint32_t*>(kvu + (size_t)sA * 256 + c);
        const uint32_t vpA = *reinterpret_cast<const uint32_t*>(kvu + (size_t)sA * 256 + 128 + c);
        const uint32_t kpB = *reinterpret_cast<const uint32_t*>(kvu + (size_t)sB * 256 + c);
        const uint32_t vpB = *reinterpret_cast<const uint32_t*>(kvu + (size_t)sB * 256 + 128 + c);
        const uint4 A0 = eaw[(size_t)i * 2 + 0], A1 = eaw[(size_t)i * 2 + 1];
        const uint4 B0 = eaw[(size_t)i * 2 + 2], B1 = eaw[(size_t)i * 2 + 3];
        const uint32_t wA[8] = {A0.x,A0.y,A0.z,A0.w, A1.x,A1.y,A1.z,A1.w};
        const uint32_t wB[8] = {B0.x,B0.y,B0.z,B0.w, B1.x,B1.y,B1.z,B1.w};
        float eA0 = 0.f, eA1 = 0.f, eB0 = 0.f, eB1 = 0.f;
        #pragma unroll
        for (int rr = 0; rr < 8; ++rr) {
            const float2 w0 = *reinterpret_cast<const float2*>(&wes[(2 * rr) * 128 + c]);
            const float2 w1 = *reinterpret_cast<const float2*>(&wes[(2 * rr + 1) * 128 + c]);
            const float2 aA = bfp(wA[rr]);
            const float2 aB = bfp(wB[rr]);
            eA0 += aA.x * w0.x + aA.y * w1.x;
            eA1 += aA.x * w0.y + aA.y * w1.y;
            eB0 += aB.x * w0.x + aB.y * w1.x;
            eB1 += aB.x * w0.y + aB.y * w1.y;
        }
        const float2 kA = bfp(kpA), vA = bfp(vpA), kB = bfp(kpB), vB = bfp(vpB);
        float pA = qp.x * (kA.x + eA0) + qp.y * (kA.y + eA1);
        float pB = qp.x * (kB.x + eB0) + qp.y * (kB.y + eB1);
        #pragma unroll
        for (int m = 1; m < 32; m <<= 1) {
            pA += __shfl_xor(pA, m, 64);
            pB += __shfl_xor(pB, m, 64);
        }
        const float exA = __expf(pA), exB = __expf(pB);
        acc0 += exA * (vA.x + eA0) + exB * (vB.x + eB0);
        acc1 += exA * (vA.y + eA1) + exB * (vB.y + eB1);
        den  += exA + exB;
    }
    if (i < end) {
        const int s = srcs[i];
        const uint32_t kp = *reinterpret_cast<const uint32_t*>(kvu + (size_t)s * 256 + c);
        const uint32_t vp = *reinterpret_cast<const uint32_t*>(kvu + (size_t)s * 256 + 128 + c);
        const uint4 A0 = eaw[(size_t)i * 2 + 0], A1 = eaw[(size_t)i * 2 + 1];
        const uint32_t wA[8] = {A0.x,A0.y,A0.z,A0.w, A1.x,A1.y,A1.z,A1.w};
        float e0 = 0.f, e1 = 0.f;
        #pragma unroll
        for (int rr = 0; rr < 8; ++rr) {
            const float2 w0 = *reinterpret_cast<const float2*>(&wes[(2 * rr) * 128 + c]);
            const float2 w1 = *reinterpret_cast<const float2*>(&wes[(2 * rr + 1) * 128 + c]);
            const float2 aA = bfp(wA[rr]);
            e0 += aA.x * w0.x + aA.y * w1.x;
            e1 += aA.x * w0.y + aA.y * w1.y;
        }
        const float2 kk = bfp(kp), vv = bfp(vp);
        float p = qp.x * (kk.x + e0) + qp.y * (kk.y + e1);
        #pragma unroll
        for (int m = 1; m < 32; m <<= 1) p += __shfl_xor(p, m, 64);
        const float ex = __expf(p);
        acc0 += ex * (vv.x + e0);
        acc1 += ex * (vv.y + e1);
        den  += ex;
    }

    const float inv = 1.f / (den + 1e-16f);
    const float2 sk = *reinterpret_cast<const float2*>(skip + nb + c);
    const float r0 = acc0 * inv + sk.x;
    const float r1 = acc1 * inv + sk.y;
    *reinterpret_cast<float2*>(h + nb + c) = make_float2(fmaxf(r0, 0.f), fmaxf(r1, 0.f));
}

// ---------------------------------------------------------------------------
// Layer-2 aggregation. One wave per dst node; two edges per iteration
// (half-wave each, channel pairs). We in LDS. Writes final output.
// ---------------------------------------------------------------------------
__global__ __launch_bounds__(256)
void agg_l2(const int* __restrict__ off, const int* __restrict__ srcs,
            const __hip_bfloat16* __restrict__ eap,    // [E,16] bf16, dst-sorted
            const float* __restrict__ We,              // [16,64]
            const float* __restrict__ q,               // [N,64], pre-scaled
            const __hip_bfloat16* __restrict__ kv,     // [N,128] k|v (bf16)
            const float* __restrict__ skip, float* __restrict__ out)
{
    __shared__ float wes[16 * 64];
    for (int i = threadIdx.x; i < 16 * 64; i += 256) wes[i] = We[i];
    __syncthreads();

    const int node = blockIdx.x * 4 + (threadIdx.x >> 6);
    const int lane = threadIdx.x & 63;
    const int half = lane >> 5;
    const int hl = lane & 31;
    const int c = hl * 2;

    const size_t nb = (size_t)node * 64;
    const float2 qp = *reinterpret_cast<const float2*>(q + nb + c);
    const uint16_t* kvu = reinterpret_cast<const uint16_t*>(kv);
    const uint4* eaw = reinterpret_cast<const uint4*>(eap);

    float acc0 = 0.f, acc1 = 0.f, den = 0.f;
    const int beg = off[node], end = off[node + 1];

    for (int i = beg; i < end; i += 2) {
        const int ii = i + half;
        const bool valid = ii < end;
        const int ie = valid ? ii : i;
        const int s = srcs[ie];
        const uint32_t kp = *reinterpret_cast<const uint32_t*>(kvu + (size_t)s * 128 + c);
        const uint32_t vp = *reinterpret_cast<const uint32_t*>(kvu + (size_t)s * 128 + 64 + c);
        const uint4 A0 = eaw[(size_t)ie * 2 + 0], A1 = eaw[(size_t)ie * 2 + 1];
        const uint32_t wA[8] = {A0.x,A0.y,A0.z,A0.w, A1.x,A1.y,A1.z,A1.w};
        float e0 = 0.f, e1 = 0.f;
        #pragma unroll
        for (int rr = 0; rr < 8; ++rr) {
            const float2 w0 = *reinterpret_cast<const float2*>(&wes[(2 * rr) * 64 + c]);
            const float2 w1 = *reinterpret_cast<const float2*>(&wes[(2 * rr + 1) * 64 + c]);
            const float2 aA = bfp(wA[rr]);
            e0 += aA.x * w0.x + aA.y * w1.x;
            e1 += aA.x * w0.y + aA.y * w1.y;
        }
        const float2 kk = bfp(kp), vv = bfp(vp);
        float p = qp.x * (kk.x + e0) + qp.y * (kk.y + e1);
        #pragma unroll
        for (int m = 1; m < 32; m <<= 1) p += __shfl_xor(p, m, 64);
        const float ex = valid ? __expf(p) : 0.f;
        acc0 += ex * (vv.x + e0);
        acc1 += ex * (vv.y + e1);
        den  += ex;
    }

    acc0 += __shfl_xor(acc0, 32, 64);
    acc1 += __shfl_xor(acc1, 32, 64);
    den  += __shfl_xor(den, 32, 64);

    if (half == 0) {
        const float inv = 1.f / (den + 1e-16f);
        const float2 sk = *reinterpret_cast<const float2*>(skip + nb + c);
        *reinterpret_cast<float2*>(out + nb + c) =
            make_float2(acc0 * inv + sk.x, acc1 * inv + sk.y);
    }
}

extern "C" void kernel_launch(void* const* d_in, const int* in_sizes, int n_in,
                              void* d_out, int out_size, void* d_ws, size_t ws_size,
                              hipStream_t stream) {
    const float* x     = (const float*)d_in[0];
    const int*   ei    = (const int*)  d_in[1];
    const float* eattr = (const float*)d_in[2];
    const float* Wq1 = (const float*)d_in[3],  *bq1 = (const float*)d_in[4];
    const float* Wk1 = (const float*)d_in[5],  *bk1 = (const float*)d_in[6];
    const float* Wv1 = (const float*)d_in[7],  *bv1 = (const float*)d_in[8];
    const float* We1 = (const float*)d_in[9];
    const float* Ws1 = (const float*)d_in[10], *bs1 = (const float*)d_in[11];
    const float* Wq2 = (const float*)d_in[12], *bq2 = (const float*)d_in[13];
    const float* Wk2 = (const float*)d_in[14], *bk2 = (const float*)d_in[15];
    const float* Wv2 = (const float*)d_in[16], *bv2 = (const float*)d_in[17];
    const float* We2 = (const float*)d_in[18];
    const float* Ws2 = (const float*)d_in[19], *bs2 = (const float*)d_in[20];

    const int* srcp = ei;
    const int* dstp = ei + NE;

    // workspace layout (~132 MB)
    float* ws = (float*)d_ws;
    const size_t NM1 = (size_t)NN * 128;
    float* q1    = ws;                      // [N,128] f32
    float* skip1 = q1 + NM1;                // [N,128] f32
    float* h     = skip1 + NM1;             // [N,128] f32
    __hip_bfloat16* kv1 = (__hip_bfloat16*)(h + NM1);         // [N,256] bf16
    __hip_bfloat16* eap = kv1 + (size_t)NN * 256;             // [E,16]  bf16
    int* srcs   = (int*)(eap + (size_t)NE * 16);              // [E]
    int* cnt    = srcs + NE;
    int* off    = cnt + NN;
    int* cursor = off + NN + 1;
    // layer-2 aliases (stream-ordered reuse of dead layer-1 buffers)
    float* q2    = q1;                      // [N,64]
    float* skip2 = skip1;                   // [N,64]
    __hip_bfloat16* kv2 = kv1;              // [N,128] bf16

    // ---- CSR build (dst-sorted srcs + bf16 edge-attr), reused by both layers
    hipMemsetAsync(cnt, 0, (size_t)NN * sizeof(int), stream);
    hist_dst<<<NE / 256, 256, 0, stream>>>(dstp, cnt);
    scan_off<<<1, 1024, 0, stream>>>(cnt, off, cursor);
    scatter_edges<<<NE / 256, 256, 0, stream>>>(dstp, srcp, eattr, cursor, srcs, eap);

    // ---- layer 1 ----
    node_gemm_qkvs<128, 128, 16><<<NN / 16, 128, 0, stream>>>(
        x, Wq1, bq1, q1, Wk1, bk1, Wv1, bv1, kv1, Ws1, bs1, skip1);
    agg_l1<<<NN / 4, 256, 0, stream>>>(off, srcs, eap, We1, q1, kv1, skip1, h);

    // ---- layer 2 ----
    node_gemm_qkvs<128, 64, 16><<<NN / 16, 128, 0, stream>>>(
        h, Wq2, bq2, q2, Wk2, bk2, Wv2, bv2, kv2, Ws2, bs2, skip2);
    agg_l2<<<NN / 4, 256, 0, stream>>>(off, srcs, eap, We2, q2, kv2, skip2, (float*)d_out);
}